// Round 13
// baseline (661.431 us; speedup 1.0000x reference)
//
#include <hip/hip_runtime.h>
#include <math.h>

// ---------------- problem constants ----------------
#define N_NODES 100000
#define BATCH   2000
#define KNBR    20
#define DF      172
#define MSGD    688
#define M3      6000
#define DH      86
#define KIN_D   516
#define NREFS   (3 * BATCH + NKV)          // 126000

// GRU GEMM: D(JP x NP) = W'(JP x KA) * Xc^T ; BM=128 x BN=256 tiles
#define KA      864
#define JP      768
#define KREAL   860
#define KSTEPS  (KA / 32)                  // 27
#define NT256_MAX ((N_NODES + 255) / 256)  // 391 (worst case)
#define NWG_GRU (NT256_MAX * 6)            // 2346 (fixed grid; early-exit)

// KV GEMM
#define NKV     120000
#define KP_KV   544
#define JKV     384
#define KVS     352
#define NKV_TILES ((NKV + 127) / 128)      // 938
#define NKV_ROWS (NKV_TILES * 128)         // 120064
#define NKV_T256 ((NKV + 255) / 256)       // 469
#define NWG_KV  (NKV_T256 * 3)             // 1407
#define KSTEPS_KV (KP_KV / 32)             // 17

typedef __bf16 bf16x8 __attribute__((ext_vector_type(8)));
typedef __bf16 bf16x4 __attribute__((ext_vector_type(4)));
typedef float  f32x4  __attribute__((ext_vector_type(4)));

// ---------------- ws layout (floats) ----------------
#define WPB_OFF   0
#define BP4_OFF   331776
#define WKV_OFF   332544
#define MU_OFF    436992            // mem_upd bf16
#define UNI_OFF   17636992          // Xb region (dead after gru); unions below
#define KV_OFF    UNI_OFF
#define QB_OFF    38756992
#define CAT_OFF   39286400
#define EMBB_OFF  40922752
#define MW1O_OFF  41812608
#define WQB_OFF   41842192
#define WM1B_OFF  41875984
#define WM2B_OFF  41909776
#define WAFFB_OFF 41928208
#define BM1P_OFF  41962000
#define BM2P_OFF  41962192
#define BAFFP_OFF 41962384
#define NODES_OFF 41962768
#define KIN_OFF   42000000          // bf16 120064 x 544
#define FLAGS_OFF 74700000
#define LIST_OFF  74800032
#define CNT_OFF   74950000

__device__ __forceinline__ float sigmoidf_(float x) { return 1.0f / (1.0f + expf(-x)); }

typedef __attribute__((address_space(1))) const void gvoid;
typedef __attribute__((address_space(3))) void svoid;
__device__ __forceinline__ void gl16(const void* g, void* l) {
    __builtin_amdgcn_global_load_lds((gvoid*)g, (svoid*)l, 16, 0, 0);
}

// ============================================================
// Kernel 0a: gate-major bf16 GRU weight W' (JP x KA) + fused bias
// ============================================================
__global__ __launch_bounds__(256) void prep_kernel(
    const float* __restrict__ w_ih, const float* __restrict__ w_hh,
    const float* __restrict__ b_ih, const float* __restrict__ b_hh,
    __bf16* __restrict__ wpb, float* __restrict__ bp4)
{
    int idx = blockIdx.x * 256 + threadIdx.x;
    if (idx < JP * KA) {
        int j = idx / KA, k = idx - j * KA;
        int d = j >> 2, g = j & 3;
        float v = 0.f;
        if (d < DF) {
            if (g == 0) {
                if (k < MSGD) v = w_ih[d * MSGD + k];
                else if (k < KREAL) v = w_hh[d * DF + (k - MSGD)];
            } else if (g == 1) {
                if (k < MSGD) v = w_ih[(d + DF) * MSGD + k];
                else if (k < KREAL) v = w_hh[(d + DF) * DF + (k - MSGD)];
            } else if (g == 2) {
                if (k < MSGD) v = w_ih[(d + 2 * DF) * MSGD + k];
            } else {
                if (k >= MSGD && k < KREAL) v = w_hh[(d + 2 * DF) * DF + (k - MSGD)];
            }
        }
        wpb[idx] = (__bf16)v;
    }
    if (idx < JP) {
        int d = idx >> 2, g = idx & 3;
        float b = 0.f;
        if (d < DF) {
            if (g == 0) b = b_ih[d] + b_hh[d];
            else if (g == 1) b = b_ih[d + DF] + b_hh[d + DF];
            else if (g == 2) b = b_ih[d + 2 * DF];
            else            b = b_hh[d + 2 * DF];
        }
        bp4[idx] = b;
    }
}

// ============================================================
// Kernel 0b: combined bf16 KV weight (JKV x KP_KV)
// ============================================================
__global__ __launch_bounds__(256) void prep_kv_kernel(
    const float* __restrict__ w_k, const float* __restrict__ w_v,
    __bf16* __restrict__ wkvb)
{
    int idx = blockIdx.x * 256 + threadIdx.x;
    if (idx < JKV * KP_KV) {
        int j = idx / KP_KV, k = idx - j * KP_KV;
        float v = 0.f;
        if (k < KIN_D) {
            if (j < DF) v = w_k[j * KIN_D + k];
            else if (j >= 192 && j < 192 + DF) v = w_v[(j - 192) * KIN_D + k];
        }
        wkvb[idx] = (__bf16)v;
    }
}

// ============================================================
// Kernel 0f/0g/0h: referenced-node dedup
// ============================================================
__global__ __launch_bounds__(256) void flag_zero_kernel(
    int* __restrict__ flags, int* __restrict__ cnt)
{
    int idx = blockIdx.x * 256 + threadIdx.x;
    if (idx < N_NODES) flags[idx] = 0;
    if (idx == 0) *cnt = 0;
}

__global__ __launch_bounds__(256) void flag_mark_kernel(
    const int* __restrict__ src_nodes, const int* __restrict__ dst_nodes,
    const int* __restrict__ neg_nodes, const int* __restrict__ neighbors,
    int* __restrict__ flags)
{
    int idx = blockIdx.x * 256 + threadIdx.x;
    if (idx >= NREFS) return;
    int node;
    if (idx < BATCH)          node = src_nodes[idx];
    else if (idx < 2 * BATCH) node = dst_nodes[idx - BATCH];
    else if (idx < 3 * BATCH) node = neg_nodes[idx - 2 * BATCH];
    else                      node = neighbors[idx - 3 * BATCH];
    flags[node] = 1;
}

__global__ __launch_bounds__(256) void compact_kernel(
    const int* __restrict__ flags, int* __restrict__ list, int* __restrict__ cnt)
{
    int idx = blockIdx.x * 256 + threadIdx.x;
    if (idx < N_NODES && flags[idx]) {
        int pos = atomicAdd(cnt, 1);
        list[pos] = idx;
    }
}

// ============================================================
// Kernel 0c: X -> bf16, COMPACTED rows (row r = node list[r])
// ============================================================
__global__ __launch_bounds__(256) void conv_kernel(
    const float* __restrict__ messages, const float* __restrict__ memory,
    const int* __restrict__ list, const int* __restrict__ cnt,
    __bf16* __restrict__ xb)
{
    const int n = *cnt;
    const long total = (long)n * (KA / 8);
    for (long idx = (long)blockIdx.x * 256 + threadIdx.x; idx < total;
         idx += (long)gridDim.x * 256) {
        const int r  = (int)(idx / (KA / 8));
        const int k  = (int)(idx - (long)r * (KA / 8)) * 8;
        const int node = list[r];
        float f[8];
        if (k < MSGD) {
            const float4 a = *(const float4*)(messages + (size_t)node * MSGD + k);
            const float4 b = *(const float4*)(messages + (size_t)node * MSGD + k + 4);
            f[0]=a.x; f[1]=a.y; f[2]=a.z; f[3]=a.w;
            f[4]=b.x; f[5]=b.y; f[6]=b.z; f[7]=b.w;
        } else {
            const int o = k - MSGD;
            const float4 a = *(const float4*)(memory + (size_t)node * DF + o);
            float4 b = make_float4(0.f, 0.f, 0.f, 0.f);
            if (o <= 164) b = *(const float4*)(memory + (size_t)node * DF + o + 4);
            f[0]=a.x; f[1]=a.y; f[2]=a.z; f[3]=a.w;
            f[4]=b.x; f[5]=b.y; f[6]=b.z; f[7]=b.w;
        }
        bf16x8 v;
#pragma unroll
        for (int j = 0; j < 8; ++j) v[j] = (__bf16)f[j];
        *(bf16x8*)(xb + (size_t)r * KA + k) = v;
    }
}

// ============================================================
// Kernel 0d: mw1o = merge_w1[:, :172] @ w_o   (172x172 f32)
// ============================================================
__global__ __launch_bounds__(256) void mw1o_kernel(
    const float* __restrict__ merge_w1, const float* __restrict__ w_o,
    float* __restrict__ mw1o)
{
    int idx = blockIdx.x * 256 + threadIdx.x;
    if (idx >= DF * DF) return;
    int j = idx / DF, k = idx - j * DF;
    float s = 0.f;
    for (int c = 0; c < DF; ++c)
        s = fmaf(merge_w1[j * 344 + c], w_o[c * DF + k], s);
    mw1o[idx] = s;
}

// ============================================================
// Kernel 0e: tail weights/biases/nodes_cat
// ============================================================
__global__ __launch_bounds__(256) void prep_tail_kernel(
    const float* __restrict__ w_q, const float* __restrict__ mw1o,
    const float* __restrict__ merge_w1, const float* __restrict__ merge_w2,
    const float* __restrict__ aff_w1,
    const float* __restrict__ merge_b1, const float* __restrict__ merge_b2,
    const float* __restrict__ aff_b1,
    const int* __restrict__ src_nodes, const int* __restrict__ dst_nodes,
    const int* __restrict__ neg_nodes,
    __bf16* __restrict__ wqb, __bf16* __restrict__ wm1b,
    __bf16* __restrict__ wm2b, __bf16* __restrict__ waffb,
    float* __restrict__ bm1p, float* __restrict__ bm2p,
    float* __restrict__ baffp, int* __restrict__ nodes_cat)
{
    int idx = blockIdx.x * 256 + threadIdx.x;
    if (idx < 192 * 352) {
        int j = idx / 352, k = idx - j * 352;
        float vq = 0.f, vm = 0.f, va = 0.f;
        if (j < DF) {
            if (k < DF) {
                vq = w_q[j * 344 + k];
                vm = mw1o[j * DF + k];
                va = aff_w1[j * 344 + k];
            } else if (k >= 176 && k < 348) {
                vq = w_q[j * 344 + 172 + (k - 176)];
                vm = merge_w1[j * 344 + 172 + (k - 176)];
                va = aff_w1[j * 344 + 172 + (k - 176)];
            }
        }
        wqb[idx] = (__bf16)vq;
        wm1b[idx] = (__bf16)vm;
        waffb[idx] = (__bf16)va;
    }
    if (idx < 192 * 192) {
        int j = idx / 192, k = idx - j * 192;
        wm2b[idx] = (__bf16)((j < DF && k < DF) ? merge_w2[j * DF + k] : 0.f);
    }
    if (idx < 192) {
        bm1p[idx]  = (idx < DF) ? merge_b1[idx] : 0.f;
        bm2p[idx]  = (idx < DF) ? merge_b2[idx] : 0.f;
        baffp[idx] = (idx < DF) ? aff_b1[idx] : 0.f;
    }
    if (idx < 6016) {
        int i = min(idx, M3 - 1);
        int node;
        if (i < BATCH)          node = src_nodes[i];
        else if (i < 2 * BATCH) node = dst_nodes[i - BATCH];
        else                    node = neg_nodes[i - 2 * BATCH];
        nodes_cat[idx] = node;
    }
}

// ============================================================
// Kernel 1: MFMA GRU GEMM v7 — BM=128 x BN=256, 512 thr / 8 waves,
//  4x4 frags/wave (16 MFMA : 8 ds_read per k-step), 3-buf gl16
//  pipeline (72 KB LDS, 2 blocks/CU = 16 waves), vmcnt(3).
//  Staging: 24 wave-loads/stage split u = w*3+qq (u<8 -> Ws, else Xs).
// ============================================================
__global__ __launch_bounds__(512) void gru_mfma7_kernel(
    const __bf16* __restrict__ xb, const __bf16* __restrict__ wpb,
    const float* __restrict__ bp4, const int* __restrict__ list,
    const int* __restrict__ cnt, __bf16* __restrict__ mem_upd)
{
    __shared__ __align__(16) __bf16 Ws[3][128 * 32];   // 24 KB
    __shared__ __align__(16) __bf16 Xs[3][256 * 32];   // 48 KB

    const int cntv = *cnt;
    const int ntiles = (cntv + 255) >> 8;

    const int t    = threadIdx.x;
    const int w    = t >> 6, lane = t & 63;
    const int lo   = lane & 15, hi = lane >> 4;
    const int wm   = w & 1;          // j half (64)
    const int wn   = w >> 1;         // n quarter (64 of 256)

    const int orig = blockIdx.x;
    const int q = NWG_GRU >> 3, rr = NWG_GRU & 7;    // 293, 2
    const int xcd = orig & 7, oidx = orig >> 3;
    const int wgid = (xcd < rr ? xcd * (q + 1) : rr * (q + 1) + (xcd - rr) * q) + oidx;
    const int m_tile = wgid % 6;
    const int n_tile = wgid / 6;
    if (n_tile >= ntiles) return;            // uniform; before any barrier
    const int n0 = n_tile * 256;
    const int j0 = m_tile * 128;

    const int srow  = lane >> 2;
    const int sslot = ((lane & 3) ^ ((srow >> 1) & 3)) * 8;

    f32x4 acc[4][4];
#pragma unroll
    for (int mi = 0; mi < 4; ++mi)
#pragma unroll
        for (int ni = 0; ni < 4; ++ni)
            acc[mi][ni] = (f32x4){0.f, 0.f, 0.f, 0.f};

    const __bf16* wbase = wpb + (size_t)j0 * KA;
    const __bf16* xbase = xb + (size_t)n0 * KA;

#define STAGE(buf, k0)                                                          \
    {                                                                           \
        _Pragma("unroll")                                                       \
        for (int qq = 0; qq < 3; ++qq) {                                        \
            const int u = w * 3 + qq;                                           \
            if (u < 8)                                                          \
                gl16(wbase + (size_t)(u * 16 + srow) * KA + (k0) + sslot,       \
                     &Ws[buf][(u * 16) * 32]);                                  \
            else                                                                \
                gl16(xbase + (size_t)((u - 8) * 16 + srow) * KA + (k0) + sslot, \
                     &Xs[buf][((u - 8) * 16) * 32]);                            \
        }                                                                       \
    }

    STAGE(0, 0);
    STAGE(1, 32);

    const int fsa = (hi ^ ((lo >> 1) & 3)) * 8;
    for (int ks = 0; ks < KSTEPS; ++ks) {
        if (ks < KSTEPS - 1) {
            asm volatile("s_waitcnt vmcnt(3)" ::: "memory");
        } else {
            asm volatile("s_waitcnt vmcnt(0)" ::: "memory");
        }
        __builtin_amdgcn_s_barrier();
        if (ks + 2 < KSTEPS) STAGE((ks + 2) % 3, (ks + 2) * 32);

        const int bi = ks % 3;
        bf16x8 af[4], bx_[4];
#pragma unroll
        for (int i = 0; i < 4; ++i)
            af[i]  = *(const bf16x8*)&Ws[bi][(wm * 64 + i * 16 + lo) * 32 + fsa];
#pragma unroll
        for (int i = 0; i < 4; ++i)
            bx_[i] = *(const bf16x8*)&Xs[bi][(wn * 64 + i * 16 + lo) * 32 + fsa];
#pragma unroll
        for (int mi = 0; mi < 4; ++mi)
#pragma unroll
            for (int ni = 0; ni < 4; ++ni)
                acc[mi][ni] = __builtin_amdgcn_mfma_f32_16x16x32_bf16(
                    af[mi], bx_[ni], acc[mi][ni], 0, 0, 0);
    }
#undef STAGE

    const int dbase = m_tile * 32 + wm * 16;
#pragma unroll
    for (int mi = 0; mi < 4; ++mi) {
        const int d = dbase + mi * 4 + hi;
        if (d >= DF) continue;
        const float4 b4 = *(const float4*)&bp4[4 * d];
#pragma unroll
        for (int ni = 0; ni < 4; ++ni) {
            const int n = n0 + wn * 64 + ni * 16 + lo;
            if (n >= cntv) continue;
            const int node = list[n];
            float sr  = acc[mi][ni][0] + b4.x;
            float sz  = acc[mi][ni][1] + b4.y;
            float gin = acc[mi][ni][2] + b4.z;
            float ghn = acc[mi][ni][3] + b4.w;
            float mem = (float)xb[(size_t)n * KA + MSGD + d];  // L2-hot bf16
            float rg  = sigmoidf_(sr);
            float zg  = sigmoidf_(sz);
            float nt  = tanhf(fmaf(rg, ghn, gin));
            mem_upd[(size_t)node * DF + d] = (__bf16)fmaf(zg, mem - nt, nt);
        }
    }
}

// ============================================================
// Kernel 2a: kin build — gather + convert + time-encode, bf16 rows.
// ============================================================
__global__ __launch_bounds__(256) void kin_build_kernel(
    const __bf16* __restrict__ mem_upd, const float* __restrict__ edge_features,
    const float* __restrict__ edge_times, const float* __restrict__ neighbor_times,
    const float* __restrict__ time_w, const float* __restrict__ time_b,
    const int* __restrict__ neighbors, const int* __restrict__ nbr_eidx,
    __bf16* __restrict__ kin)
{
    const long total = (long)NKV_ROWS * 136;
    for (long idx = (long)blockIdx.x * 256 + threadIdx.x; idx < total;
         idx += (long)gridDim.x * 256) {
        const int r  = (int)(idx / 136);
        const int c  = (int)(idx - (long)r * 136) * 4;
        const int rc = min(r, NKV - 1);
        bf16x4 o;
        if (c < DF) {
            const int nbr = neighbors[rc];
            o = *(const bf16x4*)(mem_upd + (size_t)nbr * DF + c);
        } else if (c < 2 * DF) {
            const int eidx = nbr_eidx[rc];
            const float4 v = *(const float4*)(edge_features + (size_t)eidx * DF + (c - DF));
            o[0] = (__bf16)v.x; o[1] = (__bf16)v.y;
            o[2] = (__bf16)v.z; o[3] = (__bf16)v.w;
        } else if (c < KIN_D) {
            const float dt = edge_times[(rc / KNBR) % BATCH] - neighbor_times[rc];
            const float4 tw = *(const float4*)(time_w + (c - 2 * DF));
            const float4 tb = *(const float4*)(time_b + (c - 2 * DF));
            o[0] = (__bf16)cosf(fmaf(dt, tw.x, tb.x));
            o[1] = (__bf16)cosf(fmaf(dt, tw.y, tb.y));
            o[2] = (__bf16)cosf(fmaf(dt, tw.z, tb.z));
            o[3] = (__bf16)cosf(fmaf(dt, tw.w, tb.w));
        } else {
            o[0] = o[1] = o[2] = o[3] = (__bf16)0.f;
        }
        *(bf16x4*)(kin + (size_t)r * KP_KV + c) = o;
    }
}

// ============================================================
// Kernel 2b: KV GEMM v5 — BM=128 x BN=256, 512 thr, 4x4 frags,
//  3-buf gl16 pipeline, vmcnt(3). Same structure as gru v7.
// ============================================================
__global__ __launch_bounds__(512) void kv_gemm5_kernel(
    const __bf16* __restrict__ kin, const __bf16* __restrict__ wkvb,
    __bf16* __restrict__ kv)
{
    __shared__ __align__(16) __bf16 Ws[3][128 * 32];
    __shared__ __align__(16) __bf16 Xs[3][256 * 32];

    const int t    = threadIdx.x;
    const int w    = t >> 6, lane = t & 63;
    const int lo   = lane & 15, hi = lane >> 4;
    const int wm   = w & 1;
    const int wn   = w >> 1;

    const int orig = blockIdx.x;
    const int q = NWG_KV >> 3, rr = NWG_KV & 7;     // 175, 7
    const int xcd = orig & 7, oidx = orig >> 3;
    const int wgid = (xcd < rr ? xcd * (q + 1) : rr * (q + 1) + (xcd - rr) * q) + oidx;
    const int m_tile = wgid % 3;
    const int n_tile = wgid / 3;
    const int n0 = n_tile * 256;
    const int j0 = m_tile * 128;

    const int srow  = lane >> 2;
    const int sslot = ((lane & 3) ^ ((srow >> 1) & 3)) * 8;

    f32x4 acc[4][4];
#pragma unroll
    for (int mi = 0; mi < 4; ++mi)
#pragma unroll
        for (int ni = 0; ni < 4; ++ni)
            acc[mi][ni] = (f32x4){0.f, 0.f, 0.f, 0.f};

    const __bf16* wbase = wkvb + (size_t)j0 * KP_KV;
    const __bf16* xbase = kin + (size_t)n0 * KP_KV;

#define STAGE(buf, k0)                                                             \
    {                                                                              \
        _Pragma("unroll")                                                          \
        for (int qq = 0; qq < 3; ++qq) {                                           \
            const int u = w * 3 + qq;                                              \
            if (u < 8)                                                             \
                gl16(wbase + (size_t)(u * 16 + srow) * KP_KV + (k0) + sslot,       \
                     &Ws[buf][(u * 16) * 32]);                                     \
            else                                                                   \
                gl16(xbase + (size_t)((u - 8) * 16 + srow) * KP_KV + (k0) + sslot, \
                     &Xs[buf][((u - 8) * 16) * 32]);                               \
        }                                                                          \
    }

    STAGE(0, 0);
    STAGE(1, 32);

    const int fsa = (hi ^ ((lo >> 1) & 3)) * 8;
    for (int ks = 0; ks < KSTEPS_KV; ++ks) {
        if (ks < KSTEPS_KV - 1) {
            asm volatile("s_waitcnt vmcnt(3)" ::: "memory");
        } else {
            asm volatile("s_waitcnt vmcnt(0)" ::: "memory");
        }
        __builtin_amdgcn_s_barrier();
        if (ks + 2 < KSTEPS_KV) STAGE((ks + 2) % 3, (ks + 2) * 32);

        const int bi = ks % 3;
        bf16x8 af[4], bx_[4];
#pragma unroll
        for (int i = 0; i < 4; ++i)
            af[i]  = *(const bf16x8*)&Ws[bi][(wm * 64 + i * 16 + lo) * 32 + fsa];
#pragma unroll
        for (int i = 0; i < 4; ++i)
            bx_[i] = *(const bf16x8*)&Xs[bi][(wn * 64 + i * 16 + lo) * 32 + fsa];
#pragma unroll
        for (int mi = 0; mi < 4; ++mi)
#pragma unroll
            for (int ni = 0; ni < 4; ++ni)
                acc[mi][ni] = __builtin_amdgcn_mfma_f32_16x16x32_bf16(
                    af[mi], bx_[ni], acc[mi][ni], 0, 0, 0);
    }
#undef STAGE

#pragma unroll
    for (int mi = 0; mi < 4; ++mi) {
        const int jb = j0 + wm * 64 + mi * 16 + hi * 4;
        int off;
        if (jb + 3 < DF)                 off = jb;        // K region
        else if (jb >= 192 && jb < 361)  off = jb - 16;   // V region
        else continue;
#pragma unroll
        for (int ni = 0; ni < 4; ++ni) {
            const int n = n0 + wn * 64 + ni * 16 + lo;
            if (n >= NKV) continue;
            bf16x4 o;
            o[0] = (__bf16)acc[mi][ni][0];
            o[1] = (__bf16)acc[mi][ni][1];
            o[2] = (__bf16)acc[mi][ni][2];
            o[3] = (__bf16)acc[mi][ni][3];
            *(bf16x4*)(kv + (size_t)n * KVS + off) = o;
        }
    }
}

// ============================================================
// Kernel 3: q projection GEMM v2 — single 192-j tile, 47 blocks.
// ============================================================
__global__ __launch_bounds__(256) void q_gemm_kernel(
    const __bf16* __restrict__ wqb, const __bf16* __restrict__ mem_upd,
    const float* __restrict__ time_b, const int* __restrict__ nodes_cat,
    __bf16* __restrict__ qbuf)
{
    __shared__ __align__(16) __bf16 Ws[192 * 32];
    __shared__ __align__(16) __bf16 Xs[128][32];

    const int t    = threadIdx.x;
    const int w    = t >> 6, lane = t & 63;
    const int lo   = lane & 15, hi = lane >> 4;
    const int wm   = w >> 1, wn = w & 1;
    const int n0   = blockIdx.x * 128;

    const int xrow  = t >> 1, xhalf = t & 1;
    const int nr    = min(n0 + xrow, M3 - 1);
    const __bf16* mrow = mem_upd + (size_t)nodes_cat[nr] * DF;

    const int srow  = lane >> 2;
    const int sslot = ((lane & 3) ^ ((srow >> 1) & 3)) * 8;
    const int fsa   = (hi ^ ((lo >> 1) & 3)) * 8;

    f32x4 acc[6][4];
#pragma unroll
    for (int mi = 0; mi < 6; ++mi)
#pragma unroll
        for (int ni = 0; ni < 4; ++ni)
            acc[mi][ni] = (f32x4){0.f, 0.f, 0.f, 0.f};

    for (int k0 = 0; k0 < 352; k0 += 32) {
#pragma unroll
        for (int qq = 0; qq < 3; ++qq) {
            const int jr = w * 48 + qq * 16 + srow;
            gl16(wqb + (size_t)jr * 352 + k0 + sslot, &Ws[(w * 48 + qq * 16) * 32]);
        }
        bf16x8 x0, x1;
#pragma unroll
        for (int c = 0; c < 4; ++c) {
            const int b = k0 + xhalf * 16 + c * 4;
            __bf16 e0, e1, e2, e3;
            if (b + 3 < DF) {
                bf16x4 h = *(const bf16x4*)(mrow + b);
                e0 = h[0]; e1 = h[1]; e2 = h[2]; e3 = h[3];
            } else if (b >= 176 && b < 348) {
                const float4 tb = *(const float4*)(time_b + (b - 176));
                e0 = (__bf16)cosf(tb.x); e1 = (__bf16)cosf(tb.y);
                e2 = (__bf16)cosf(tb.z); e3 = (__bf16)cosf(tb.w);
            } else {
                e0 = e1 = e2 = e3 = (__bf16)0.f;
            }
            if (c < 2) { x0[c*4]=e0; x0[c*4+1]=e1; x0[c*4+2]=e2; x0[c*4+3]=e3; }
            else { x1[(c-2)*4]=e0; x1[(c-2)*4+1]=e1; x1[(c-2)*4+2]=e2; x1[(c-2)*4+3]=e3; }
        }
        *(bf16x8*)&Xs[xrow][xhalf * 16]     = x0;
        *(bf16x8*)&Xs[xrow][xhalf * 16 + 8] = x1;
        __syncthreads();

        bf16x8 af[6], bx_[4];
#pragma unroll
        for (int i = 0; i < 6; ++i)
            af[i] = *(const bf16x8*)&Ws[(wm * 96 + i * 16 + lo) * 32 + fsa];
#pragma unroll
        for (int i = 0; i < 4; ++i)
            bx_[i] = *(const bf16x8*)&Xs[wn * 64 + i * 16 + lo][hi * 8];
#pragma unroll
        for (int mi = 0; mi < 6; ++mi)
#pragma unroll
            for (int ni = 0; ni < 4; ++ni)
                acc[mi][ni] = __builtin_amdgcn_mfma_f32_16x16x32_bf16(
                    af[mi], bx_[ni], acc[mi][ni], 0, 0, 0);
        __syncthreads();
    }

#pragma unroll
    for (int mi = 0; mi < 6; ++mi) {
        const int jb = wm * 96 + mi * 16 + hi * 4;
        if (jb + 3 >= 176) continue;
#pragma unroll
        for (int ni = 0; ni < 4; ++ni) {
            const int n = n0 + wn * 64 + ni * 16 + lo;
            if (n >= M3) continue;
            bf16x4 o;
            o[0]=(__bf16)acc[mi][ni][0]; o[1]=(__bf16)acc[mi][ni][1];
            o[2]=(__bf16)acc[mi][ni][2]; o[3]=(__bf16)acc[mi][ni][3];
            *(bf16x4*)(qbuf + (size_t)n * 176 + jb) = o;
        }
    }
}

// ============================================================
// Kernel 4: attn_mid v2 — 2 queries per block (3000 blocks)
// ============================================================
__global__ __launch_bounds__(256) void attn_mid_kernel(
    const __bf16* __restrict__ mem_upd, const __bf16* __restrict__ kv,
    const __bf16* __restrict__ qb, const int* __restrict__ neighbors,
    const int* __restrict__ nodes_cat, __bf16* __restrict__ cat)
{
    __shared__ __align__(16) __bf16 kvs[2][KNBR][KVS];
    __shared__ float qs[2][176];
    __shared__ float scl[2][2][KNBR];
    __shared__ float attnl[2][2][KNBR];
    __shared__ int   nbrs[2][KNBR];

    const int i0 = blockIdx.x * 2;
    const int t = threadIdx.x;

    if (t < 2 * KNBR) {
        int q = t / KNBR, kn = t - q * KNBR;
        nbrs[q][kn] = neighbors[(i0 + q) * KNBR + kn];
    }
    for (int idx = t; idx < 352; idx += 256) {
        int q = idx / 176, c = idx - q * 176;
        qs[q][c] = (float)qb[(size_t)(i0 + q) * 176 + c];
    }
    {
        const uint4* src = (const uint4*)(kv + (size_t)i0 * KNBR * KVS);
        uint4* dst = (uint4*)&kvs[0][0][0];
        for (int idx = t; idx < 2 * KNBR * KVS / 8; idx += 256) dst[idx] = src[idx];
    }
    __syncthreads();

    if (t < 4 * KNBR) {
        int q = t / (2 * KNBR);
        int r = t - q * 2 * KNBR;
        int h = r / KNBR, kn = r - h * KNBR;
        float s = 0.f;
#pragma unroll 2
        for (int j = 0; j < DH; ++j)
            s = fmaf(qs[q][h * DH + j], (float)kvs[q][kn][h * DH + j], s);
        s /= sqrtf((float)DH);
        scl[q][h][kn] = (nbrs[q][kn] > 0) ? s : -1e9f;
    }
    __syncthreads();
    if (t < 4) {
        int q = t >> 1, h = t & 1;
        float m = -INFINITY;
        for (int kn = 0; kn < KNBR; ++kn) m = fmaxf(m, scl[q][h][kn]);
        float se = 0.f;
        for (int kn = 0; kn < KNBR; ++kn) se += expf(scl[q][h][kn] - m);
        float inv = 1.f / se;
        for (int kn = 0; kn < KNBR; ++kn)
            attnl[q][h][kn] = expf(scl[q][h][kn] - m) * inv;
    }
    __syncthreads();
    for (int idx = t; idx < 2 * DF; idx += 256) {
        int q = idx / DF, d = idx - q * DF;
        int h = d / DH;
        float cx = 0.f;
#pragma unroll
        for (int kn = 0; kn < KNBR; ++kn)
            cx = fmaf(attnl[q][h][kn], (float)kvs[q][kn][176 + d], cx);
        cat[(size_t)(i0 + q) * 352 + d] = (__bf16)cx;
        cat[(size_t)(i0 + q) * 352 + 176 + d] =
            mem_upd[(size_t)nodes_cat[i0 + q] * DF + d];
    }
    if (t < 8) {
        int q = t >> 2, r = t & 3;
        cat[(size_t)(i0 + q) * 352 + 172 + r] = (__bf16)0.f;
        cat[(size_t)(i0 + q) * 352 + 348 + r] = (__bf16)0.f;
    }
}

// ============================================================
// Kernel 5: fused merge+emb — 64-row n-tiles (94 blocks)
// ============================================================
__global__ __launch_bounds__(256) void merge_emb_kernel(
    const __bf16* __restrict__ cat, const __bf16* __restrict__ wm1b,
    const __bf16* __restrict__ wm2b, const float* __restrict__ bm1p,
    const float* __restrict__ bm2p, __bf16* __restrict__ embb)
{
    __shared__ __align__(16) __bf16 Ws[192 * 32];
    __shared__ __align__(16) __bf16 Xs[64 * 32];
    __shared__ __align__(16) __bf16 h1[64 * 200];

    const int t    = threadIdx.x;
    const int w    = t >> 6, lane = t & 63;
    const int lo   = lane & 15, hi = lane >> 4;
    const int wm   = w >> 1, wn = w & 1;
    const int n0   = blockIdx.x * 64;

    const int srow  = lane >> 2;
    const int sslot = ((lane & 3) ^ ((srow >> 1) & 3)) * 8;
    const int fsa   = (hi ^ ((lo >> 1) & 3)) * 8;

    f32x4 acc[6][2];
#pragma unroll
    for (int mi = 0; mi < 6; ++mi)
#pragma unroll
        for (int ni = 0; ni < 2; ++ni)
            acc[mi][ni] = (f32x4){0.f, 0.f, 0.f, 0.f};

    for (int k0 = 0; k0 < 352; k0 += 32) {
#pragma unroll
        for (int qq = 0; qq < 3; ++qq) {
            const int jr = w * 48 + qq * 16 + srow;
            gl16(wm1b + (size_t)jr * 352 + k0 + sslot, &Ws[(w * 48 + qq * 16) * 32]);
        }
        {
            const int r = w * 16 + srow;
            const int nr = min(n0 + r, M3 - 1);
            gl16(cat + (size_t)nr * 352 + k0 + sslot, &Xs[(w * 16) * 32]);
        }
        asm volatile("s_waitcnt vmcnt(0)" ::: "memory");
        __syncthreads();

        bf16x8 af[6], bx_[2];
#pragma unroll
        for (int i = 0; i < 6; ++i)
            af[i] = *(const bf16x8*)&Ws[(wm * 96 + i * 16 + lo) * 32 + fsa];
#pragma unroll
        for (int i = 0; i < 2; ++i)
            bx_[i] = *(const bf16x8*)&Xs[(wn * 32 + i * 16 + lo) * 32 + fsa];
#pragma unroll
        for (int mi = 0; mi < 6; ++mi)
#pragma unroll
            for (int ni = 0; ni < 2; ++ni)
                acc[mi][ni] = __builtin_amdgcn_mfma_f32_16x16x32_bf16(
                    af[mi], bx_[ni], acc[mi][ni], 0, 0, 0);
        __syncthreads();
    }

#pragma unroll
    for (int mi = 0; mi < 6; ++mi) {
        const int jb = wm * 96 + mi * 16 + hi * 4;
        const float4 b4 = *(const float4*)(bm1p + jb);
#pragma unroll
        for (int ni = 0; ni < 2; ++ni) {
            const int nl = wn * 32 + ni * 16 + lo;
            bf16x4 o;
            o[0] = (__bf16)fmaxf(acc[mi][ni][0] + b4.x, 0.f);
            o[1] = (__bf16)fmaxf(acc[mi][ni][1] + b4.y, 0.f);
            o[2] = (__bf16)fmaxf(acc[mi][ni][2] + b4.z, 0.f);
            o[3] = (__bf16)fmaxf(acc[mi][ni][3] + b4.w, 0.f);
            *(bf16x4*)&h1[nl * 200 + jb] = o;
        }
    }
    __syncthreads();

    f32x4 acc2[6][2];
#pragma unroll
    for (int mi = 0; mi < 6; ++mi)
#pragma unroll
        for (int ni = 0; ni < 2; ++ni)
            acc2[mi][ni] = (f32x4){0.f, 0.f, 0.f, 0.f};

    for (int k0 = 0; k0 < 192; k0 += 32) {
#pragma unroll
        for (int qq = 0; qq < 3; ++qq) {
            const int jr = w * 48 + qq * 16 + srow;
            gl16(wm2b + (size_t)jr * 192 + k0 + sslot, &Ws[(w * 48 + qq * 16) * 32]);
        }
        asm volatile("s_waitcnt vmcnt(0)" ::: "memory");
        __syncthreads();

        bf16x8 af[6], bx_[2];
#pragma unroll
        for (int i = 0; i < 6; ++i)
            af[i] = *(const bf16x8*)&Ws[(wm * 96 + i * 16 + lo) * 32 + fsa];
#pragma unroll
        for (int i = 0; i < 2; ++i)
            bx_[i] = *(const bf16x8*)&h1[(wn * 32 + i * 16 + lo) * 200 + k0 + hi * 8];
#pragma unroll
        for (int mi = 0; mi < 6; ++mi)
#pragma unroll
            for (int ni = 0; ni < 2; ++ni)
                acc2[mi][ni] = __builtin_amdgcn_mfma_f32_16x16x32_bf16(
                    af[mi], bx_[ni], acc2[mi][ni], 0, 0, 0);
        __syncthreads();
    }

#pragma unroll
    for (int mi = 0; mi < 6; ++mi) {
        const int jb = wm * 96 + mi * 16 + hi * 4;
        if (jb + 3 >= 176) continue;
        const float4 b4 = *(const float4*)(bm2p + jb);
#pragma unroll
        for (int ni = 0; ni < 2; ++ni) {
            const int n = n0 + wn * 32 + ni * 16 + lo;
            if (n >= M3) continue;
            bf16x4 o;
            o[0] = (__bf16)(acc2[mi][ni][0] + b4.x);
            o[1] = (__bf16)(acc2[mi][ni][1] + b4.y);
            o[2] = (__bf16)(acc2[mi][ni][2] + b4.z);
            o[3] = (__bf16)(acc2[mi][ni][3] + b4.w);
            *(bf16x4*)(embb + (size_t)n * 176 + jb) = o;
        }
    }
}

// ============================================================
// Kernel 6: fused affinity GEMM + dot + sigmoid (32 blocks)
// ============================================================
__global__ __launch_bounds__(256) void aff_fused_kernel(
    const __bf16* __restrict__ embb, const __bf16* __restrict__ waffb,
    const float* __restrict__ baffp, const float* __restrict__ aff_w2,
    const float* __restrict__ aff_b2, float* __restrict__ out)
{
    __shared__ __align__(16) __bf16 Ws[192 * 32];
    __shared__ __align__(16) __bf16 Xs[128 * 32];
    __shared__ float sred[2][2][4][16];

    const int t    = threadIdx.x;
    const int w    = t >> 6, lane = t & 63;
    const int lo   = lane & 15, hi = lane >> 4;
    const int wm   = w >> 1, wn = w & 1;
    const int n0   = blockIdx.x * 128;

    const int srow  = lane >> 2;
    const int sslot = ((lane & 3) ^ ((srow >> 1) & 3)) * 8;
    const int fsa   = (hi ^ ((lo >> 1) & 3)) * 8;

    f32x4 acc[6][4];
#pragma unroll
    for (int mi = 0; mi < 6; ++mi)
#pragma unroll
        for (int ni = 0; ni < 4; ++ni)
            acc[mi][ni] = (f32x4){0.f, 0.f, 0.f, 0.f};

    for (int k0 = 0; k0 < 352; k0 += 32) {
#pragma unroll
        for (int qq = 0; qq < 3; ++qq) {
            const int jr = w * 48 + qq * 16 + srow;
            gl16(waffb + (size_t)jr * 352 + k0 + sslot, &Ws[(w * 48 + qq * 16) * 32]);
        }
#pragma unroll
        for (int qq = 0; qq < 2; ++qq) {
            const int r = w * 32 + qq * 16 + srow;
            const int nr = min(n0 + r, 2 * BATCH - 1);
            const int s  = (nr < BATCH) ? nr : nr - BATCH;
            const int col = k0 + sslot;
            const __bf16* src = (col < 176)
                ? embb + (size_t)s * 176 + col
                : embb + (size_t)(nr + BATCH) * 176 + (col - 176);
            gl16(src, &Xs[(w * 32 + qq * 16) * 32]);
        }
        asm volatile("s_waitcnt vmcnt(0)" ::: "memory");
        __syncthreads();

        bf16x8 af[6], bx_[4];
#pragma unroll
        for (int i = 0; i < 6; ++i)
            af[i] = *(const bf16x8*)&Ws[(wm * 96 + i * 16 + lo) * 32 + fsa];
#pragma unroll
        for (int i = 0; i < 4; ++i)
            bx_[i] = *(const bf16x8*)&Xs[(wn * 64 + i * 16 + lo) * 32 + fsa];
#pragma unroll
        for (int mi = 0; mi < 6; ++mi)
#pragma unroll
            for (int ni = 0; ni < 4; ++ni)
                acc[mi][ni] = __builtin_amdgcn_mfma_f32_16x16x32_bf16(
                    af[mi], bx_[ni], acc[mi][ni], 0, 0, 0);
        __syncthreads();
    }

    float ps[4] = {0.f, 0.f, 0.f, 0.f};
#pragma unroll
    for (int mi = 0; mi < 6; ++mi) {
        const int jb = wm * 96 + mi * 16 + hi * 4;
#pragma unroll
        for (int r = 0; r < 4; ++r) {
            const int j = jb + r;
            const float w2v = (j < DF) ? aff_w2[j] : 0.f;
            const float bb  = baffp[j];
#pragma unroll
            for (int ni = 0; ni < 4; ++ni)
                ps[ni] += fmaxf(acc[mi][ni][r] + bb, 0.f) * w2v;
        }
    }
#pragma unroll
    for (int ni = 0; ni < 4; ++ni) {
        ps[ni] += __shfl_xor(ps[ni], 16, 64);
        ps[ni] += __shfl_xor(ps[ni], 32, 64);
    }
    if (hi == 0) {
#pragma unroll
        for (int ni = 0; ni < 4; ++ni) sred[wm][wn][ni][lo] = ps[ni];
    }
    __syncthreads();
    if (t < 128) {
        const int n = n0 + t;
        if (n < 2 * BATCH) {
            const int wn2 = t >> 6, ni = (t >> 4) & 3, lo2 = t & 15;
            float s = sred[0][wn2][ni][lo2] + sred[1][wn2][ni][lo2] + aff_b2[0];
            out[n] = 1.f / (1.f + expf(-s));
        }
    }
}

// ============================================================
extern "C" void kernel_launch(void* const* d_in, const int* in_sizes, int n_in,
                              void* d_out, int out_size, void* d_ws, size_t ws_size,
                              hipStream_t stream)
{
    (void)in_sizes; (void)n_in; (void)out_size; (void)ws_size;
    const float* memory         = (const float*)d_in[0];
    const float* messages       = (const float*)d_in[1];
    const float* edge_features  = (const float*)d_in[2];
    const float* edge_times     = (const float*)d_in[3];
    const float* neighbor_times = (const float*)d_in[4];
    const float* time_w         = (const float*)d_in[5];
    const float* time_b         = (const float*)d_in[6];
    const float* gru_w_ih       = (const float*)d_in[7];
    const float* gru_w_hh       = (const float*)d_in[8];
    const float* gru_b_ih       = (const float*)d_in[9];
    const float* gru_b_hh       = (const float*)d_in[10];
    const float* w_q            = (const float*)d_in[11];
    const float* w_k            = (const float*)d_in[12];
    const float* w_v            = (const float*)d_in[13];
    const float* w_o            = (const float*)d_in[14];
    const float* merge_w1       = (const float*)d_in[15];
    const float* merge_b1       = (const float*)d_in[16];
    const float* merge_w2       = (const float*)d_in[17];
    const float* merge_b2       = (const float*)d_in[18];
    const float* aff_w1         = (const float*)d_in[19];
    const float* aff_b1         = (const float*)d_in[20];
    const float* aff_w2         = (const float*)d_in[21];
    const float* aff_b2         = (const float*)d_in[22];
    const int* src_nodes        = (const int*)d_in[23];
    const int* dst_nodes        = (const int*)d_in[24];
    const int* neg_nodes        = (const int*)d_in[25];
    const int* neighbors        = (const int*)d_in[26];
    const int* nbr_eidx         = (const int*)d_in[27];

    float* ws       = (float*)d_ws;
    __bf16* wpb     = (__bf16*)(ws + WPB_OFF);
    float* bp4      = ws + BP4_OFF;
    __bf16* wkvb    = (__bf16*)(ws + WKV_OFF);
    __bf16* mem_upd = (__bf16*)(ws + MU_OFF);
    __bf16* xbuf    = (__bf16*)(ws + UNI_OFF);
    __bf16* kv      = (__bf16*)(ws + KV_OFF);
    __bf16* qbuf    = (__bf16*)(ws + QB_OFF);
    __bf16* cat     = (__bf16*)(ws + CAT_OFF);
    __bf16* embb    = (__bf16*)(ws + EMBB_OFF);
    float* mw1o     = ws + MW1O_OFF;
    __bf16* wqb     = (__bf16*)(ws + WQB_OFF);
    __bf16* wm1b    = (__bf16*)(ws + WM1B_OFF);
    __bf16* wm2b    = (__bf16*)(ws + WM2B_OFF);
    __bf16* waffb   = (__bf16*)(ws + WAFFB_OFF);
    float* bm1p     = ws + BM1P_OFF;
    float* bm2p     = ws + BM2P_OFF;
    float* baffp    = ws + BAFFP_OFF;
    int*   nodes_cat= (int*)(ws + NODES_OFF);
    __bf16* kin     = (__bf16*)(ws + KIN_OFF);
    int*   flags    = (int*)(ws + FLAGS_OFF);
    int*   list     = (int*)(ws + LIST_OFF);
    int*   cnt      = (int*)(ws + CNT_OFF);
    float* out      = (float*)d_out;

    flag_zero_kernel<<<(N_NODES + 255) / 256, 256, 0, stream>>>(flags, cnt);
    flag_mark_kernel<<<(NREFS + 255) / 256, 256, 0, stream>>>(
        src_nodes, dst_nodes, neg_nodes, neighbors, flags);
    compact_kernel<<<(N_NODES + 255) / 256, 256, 0, stream>>>(flags, list, cnt);

    prep_kernel<<<(JP * KA + 255) / 256, 256, 0, stream>>>(
        gru_w_ih, gru_w_hh, gru_b_ih, gru_b_hh, wpb, bp4);
    prep_kv_kernel<<<(JKV * KP_KV + 255) / 256, 256, 0, stream>>>(w_k, w_v, wkvb);
    conv_kernel<<<2048, 256, 0, stream>>>(messages, memory, list, cnt, xbuf);
    gru_mfma7_kernel<<<NWG_GRU, 512, 0, stream>>>(xbuf, wpb, bp4, list, cnt, mem_upd);
    mw1o_kernel<<<(DF * DF + 255) / 256, 256, 0, stream>>>(merge_w1, w_o, mw1o);
    prep_tail_kernel<<<(192 * 352 + 255) / 256, 256, 0, stream>>>(
        w_q, mw1o, merge_w1, merge_w2, aff_w1, merge_b1, merge_b2, aff_b1,
        src_nodes, dst_nodes, neg_nodes,
        wqb, wm1b, wm2b, waffb, bm1p, bm2p, baffp, nodes_cat);
    kin_build_kernel<<<2048, 256, 0, stream>>>(
        mem_upd, edge_features, edge_times, neighbor_times, time_w, time_b,
        neighbors, nbr_eidx, kin);
    kv_gemm5_kernel<<<NWG_KV, 512, 0, stream>>>(kin, wkvb, kv);
    q_gemm_kernel<<<47, 256, 0, stream>>>(wqb, mem_upd, time_b, nodes_cat, qbuf);
    attn_mid_kernel<<<M3 / 2, 256, 0, stream>>>(
        mem_upd, kv, qbuf, neighbors, nodes_cat, cat);
    merge_emb_kernel<<<94, 256, 0, stream>>>(cat, wm1b, wm2b, bm1p, bm2p, embb);
    aff_fused_kernel<<<32, 256, 0, stream>>>(embb, waffb, baffp, aff_w2, aff_b2, out);
}

// Round 14
// 632.720 us; speedup vs baseline: 1.0454x; 1.0454x over previous
//
#include <hip/hip_runtime.h>
#include <math.h>

// ---------------- problem constants ----------------
#define N_NODES 100000
#define BATCH   2000
#define KNBR    20
#define DF      172
#define MSGD    688
#define M3      6000
#define DH      86
#define KIN_D   516

// GRU GEMM: D(JP x NP) = W'(JP x KA) * Xb^T ; 128x128 tiles (R11-proven)
#define KA      864
#define JP      768
#define KREAL   860
#define KSTEPS  (KA / 32)                  // 27
#define NTILES_N ((N_NODES + 127) / 128)   // 782
#define NWG_GRU (NTILES_N * 6)             // 4692

// KV GEMM
#define NKV     120000
#define KP_KV   544
#define JKV     384
#define KVS     352
#define NKV_TILES ((NKV + 127) / 128)      // 938
#define NKV_ROWS (NKV_TILES * 128)         // 120064
#define NWG_KV  (NKV_TILES * 3)            // 2814
#define KSTEPS_KV (KP_KV / 32)             // 17

typedef __bf16 bf16x8 __attribute__((ext_vector_type(8)));
typedef __bf16 bf16x4 __attribute__((ext_vector_type(4)));
typedef float  f32x4  __attribute__((ext_vector_type(4)));

// ---------------- ws layout (floats) ----------------
#define WPB_OFF   0
#define BP4_OFF   331776
#define WKV_OFF   332544
#define MU_OFF    436992            // mem_upd bf16
#define UNI_OFF   17636992          // Xb region (dead after gru); unions below
#define KV_OFF    UNI_OFF
#define QB_OFF    38756992
#define CAT_OFF   39286400
#define EMBB_OFF  40922752
#define WQB_OFF   41842192
#define WM1B_OFF  41875984
#define WM2B_OFF  41909776
#define WAFFB_OFF 41928208
#define BM1P_OFF  41962000
#define BM2P_OFF  41962192
#define BAFFP_OFF 41962384
#define NODES_OFF 41962768
#define KIN_OFF   42000000          // bf16 120064 x 544

__device__ __forceinline__ float sigmoidf_(float x) { return 1.0f / (1.0f + expf(-x)); }

typedef __attribute__((address_space(1))) const void gvoid;
typedef __attribute__((address_space(3))) void svoid;
__device__ __forceinline__ void gl16(const void* g, void* l) {
    __builtin_amdgcn_global_load_lds((gvoid*)g, (svoid*)l, 16, 0, 0);
}

// ============================================================
// Kernel 0a: combined weight prep — GRU W' (gate-major) + bias,
//  and KV weight, in one launch (disjoint idx ranges).
// ============================================================
__global__ __launch_bounds__(256) void prep_all_kernel(
    const float* __restrict__ w_ih, const float* __restrict__ w_hh,
    const float* __restrict__ b_ih, const float* __restrict__ b_hh,
    const float* __restrict__ w_k, const float* __restrict__ w_v,
    __bf16* __restrict__ wpb, float* __restrict__ bp4,
    __bf16* __restrict__ wkvb)
{
    int idx = blockIdx.x * 256 + threadIdx.x;
    if (idx < JP * KA) {
        int j = idx / KA, k = idx - j * KA;
        int d = j >> 2, g = j & 3;
        float v = 0.f;
        if (d < DF) {
            if (g == 0) {
                if (k < MSGD) v = w_ih[d * MSGD + k];
                else if (k < KREAL) v = w_hh[d * DF + (k - MSGD)];
            } else if (g == 1) {
                if (k < MSGD) v = w_ih[(d + DF) * MSGD + k];
                else if (k < KREAL) v = w_hh[(d + DF) * DF + (k - MSGD)];
            } else if (g == 2) {
                if (k < MSGD) v = w_ih[(d + 2 * DF) * MSGD + k];
            } else {
                if (k >= MSGD && k < KREAL) v = w_hh[(d + 2 * DF) * DF + (k - MSGD)];
            }
        }
        wpb[idx] = (__bf16)v;
    }
    if (idx < JP) {
        int d = idx >> 2, g = idx & 3;
        float b = 0.f;
        if (d < DF) {
            if (g == 0) b = b_ih[d] + b_hh[d];
            else if (g == 1) b = b_ih[d + DF] + b_hh[d + DF];
            else if (g == 2) b = b_ih[d + 2 * DF];
            else            b = b_hh[d + 2 * DF];
        }
        bp4[idx] = b;
    }
    if (idx < JKV * KP_KV) {
        int j = idx / KP_KV, k = idx - j * KP_KV;
        float v = 0.f;
        if (k < KIN_D) {
            if (j < DF) v = w_k[j * KIN_D + k];
            else if (j >= 192 && j < 192 + DF) v = w_v[(j - 192) * KIN_D + k];
        }
        wkvb[idx] = (__bf16)v;
    }
}

// ============================================================
// Kernel 0c: X -> bf16 (all nodes; R11-proven)
// ============================================================
__global__ __launch_bounds__(256) void conv_kernel(
    const float* __restrict__ messages, const float* __restrict__ memory,
    __bf16* __restrict__ xb)
{
    const long total = (long)N_NODES * (KA / 8);
    for (long idx = (long)blockIdx.x * 256 + threadIdx.x; idx < total;
         idx += (long)gridDim.x * 256) {
        const int r  = (int)(idx / (KA / 8));
        const int k  = (int)(idx - (long)r * (KA / 8)) * 8;
        float f[8];
        if (k < MSGD) {
            const float4 a = *(const float4*)(messages + (size_t)r * MSGD + k);
            const float4 b = *(const float4*)(messages + (size_t)r * MSGD + k + 4);
            f[0]=a.x; f[1]=a.y; f[2]=a.z; f[3]=a.w;
            f[4]=b.x; f[5]=b.y; f[6]=b.z; f[7]=b.w;
        } else {
            const int o = k - MSGD;
            const float4 a = *(const float4*)(memory + (size_t)r * DF + o);
            float4 b = make_float4(0.f, 0.f, 0.f, 0.f);
            if (o <= 164) b = *(const float4*)(memory + (size_t)r * DF + o + 4);
            f[0]=a.x; f[1]=a.y; f[2]=a.z; f[3]=a.w;
            f[4]=b.x; f[5]=b.y; f[6]=b.z; f[7]=b.w;
        }
        bf16x8 v;
#pragma unroll
        for (int j = 0; j < 8; ++j) v[j] = (__bf16)f[j];
        *(bf16x8*)(xb + (size_t)r * KA + k) = v;
    }
}

// ============================================================
// Kernel 0e: tail weights/biases/nodes_cat; mw1o computed INLINE
//  (vm for k<DF is dot(merge_w1[j,:172], w_o[:,k]) — 172 FMA/elem)
// ============================================================
__global__ __launch_bounds__(256) void prep_tail_kernel(
    const float* __restrict__ w_q, const float* __restrict__ w_o,
    const float* __restrict__ merge_w1, const float* __restrict__ merge_w2,
    const float* __restrict__ aff_w1,
    const float* __restrict__ merge_b1, const float* __restrict__ merge_b2,
    const float* __restrict__ aff_b1,
    const int* __restrict__ src_nodes, const int* __restrict__ dst_nodes,
    const int* __restrict__ neg_nodes,
    __bf16* __restrict__ wqb, __bf16* __restrict__ wm1b,
    __bf16* __restrict__ wm2b, __bf16* __restrict__ waffb,
    float* __restrict__ bm1p, float* __restrict__ bm2p,
    float* __restrict__ baffp, int* __restrict__ nodes_cat)
{
    int idx = blockIdx.x * 256 + threadIdx.x;
    if (idx < 192 * 352) {
        int j = idx / 352, k = idx - j * 352;
        float vq = 0.f, vm = 0.f, va = 0.f;
        if (j < DF) {
            if (k < DF) {
                vq = w_q[j * 344 + k];
                va = aff_w1[j * 344 + k];
                // mw1o[j][k] = merge_w1[j, :172] @ w_o[:, k]
                float s = 0.f;
#pragma unroll 4
                for (int c = 0; c < DF; ++c)
                    s = fmaf(merge_w1[j * 344 + c], w_o[c * DF + k], s);
                vm = s;
            } else if (k >= 176 && k < 348) {
                vq = w_q[j * 344 + 172 + (k - 176)];
                vm = merge_w1[j * 344 + 172 + (k - 176)];
                va = aff_w1[j * 344 + 172 + (k - 176)];
            }
        }
        wqb[idx] = (__bf16)vq;
        wm1b[idx] = (__bf16)vm;
        waffb[idx] = (__bf16)va;
    }
    if (idx < 192 * 192) {
        int j = idx / 192, k = idx - j * 192;
        wm2b[idx] = (__bf16)((j < DF && k < DF) ? merge_w2[j * DF + k] : 0.f);
    }
    if (idx < 192) {
        bm1p[idx]  = (idx < DF) ? merge_b1[idx] : 0.f;
        bm2p[idx]  = (idx < DF) ? merge_b2[idx] : 0.f;
        baffp[idx] = (idx < DF) ? aff_b1[idx] : 0.f;
    }
    if (idx < 6016) {
        int i = min(idx, M3 - 1);
        int node;
        if (i < BATCH)          node = src_nodes[i];
        else if (i < 2 * BATCH) node = dst_nodes[i - BATCH];
        else                    node = neg_nodes[i - 2 * BATCH];
        nodes_cat[idx] = node;
    }
}

// ============================================================
// Kernel 1: MFMA GRU GEMM v5b (R11-proven) — 512 thr / 8 waves,
//  3-buf gl16 pipeline, vmcnt(2), bf16 out, memory read from xbuf.
// ============================================================
__global__ __launch_bounds__(512) void gru_mfma5_kernel(
    const __bf16* __restrict__ xb, const __bf16* __restrict__ wpb,
    const float* __restrict__ bp4, __bf16* __restrict__ mem_upd)
{
    __shared__ __align__(16) __bf16 Ws[3][128 * 32];   // 24 KB
    __shared__ __align__(16) __bf16 Xs[3][128 * 32];   // 24 KB

    const int t    = threadIdx.x;
    const int w    = t >> 6, lane = t & 63;
    const int lo   = lane & 15, hi = lane >> 4;
    const int wm   = w & 1;          // j half
    const int wn   = w >> 1;         // n quarter

    const int orig = blockIdx.x;
    const int q = NWG_GRU >> 3, rr = NWG_GRU & 7;
    const int xcd = orig & 7, oidx = orig >> 3;
    const int wgid = (xcd < rr ? xcd * (q + 1) : rr * (q + 1) + (xcd - rr) * q) + oidx;
    const int m_tile = wgid % 6;
    const int n_tile = wgid / 6;
    const int n0 = n_tile * 128;
    const int j0 = m_tile * 128;

    const int srow  = lane >> 2;
    const int sslot = ((lane & 3) ^ ((srow >> 1) & 3)) * 8;

    f32x4 acc[4][2];
#pragma unroll
    for (int mi = 0; mi < 4; ++mi)
#pragma unroll
        for (int ni = 0; ni < 2; ++ni)
            acc[mi][ni] = (f32x4){0.f, 0.f, 0.f, 0.f};

    const __bf16* wbase = wpb + (size_t)j0 * KA;
    const __bf16* xbase = xb + (size_t)n0 * KA;

#define STAGE(buf, k0)                                                          \
    {                                                                           \
        const int lr = w * 16 + srow;                                           \
        gl16(wbase + (size_t)lr * KA + (k0) + sslot, &Ws[buf][(w * 16) * 32]);  \
        gl16(xbase + (size_t)lr * KA + (k0) + sslot, &Xs[buf][(w * 16) * 32]);  \
    }

    STAGE(0, 0);
    STAGE(1, 32);

    const int fsa = (hi ^ ((lo >> 1) & 3)) * 8;
    for (int ks = 0; ks < KSTEPS; ++ks) {
        if (ks < KSTEPS - 1) {
            asm volatile("s_waitcnt vmcnt(2)" ::: "memory");
        } else {
            asm volatile("s_waitcnt vmcnt(0)" ::: "memory");
        }
        __builtin_amdgcn_s_barrier();
        if (ks + 2 < KSTEPS) STAGE((ks + 2) % 3, (ks + 2) * 32);

        const int bi = ks % 3;
        bf16x8 af[4], bx_[2];
#pragma unroll
        for (int i = 0; i < 4; ++i)
            af[i]  = *(const bf16x8*)&Ws[bi][(wm * 64 + i * 16 + lo) * 32 + fsa];
#pragma unroll
        for (int i = 0; i < 2; ++i)
            bx_[i] = *(const bf16x8*)&Xs[bi][(wn * 32 + i * 16 + lo) * 32 + fsa];
#pragma unroll
        for (int mi = 0; mi < 4; ++mi)
#pragma unroll
            for (int ni = 0; ni < 2; ++ni)
                acc[mi][ni] = __builtin_amdgcn_mfma_f32_16x16x32_bf16(
                    af[mi], bx_[ni], acc[mi][ni], 0, 0, 0);
    }
#undef STAGE

    const int dbase = m_tile * 32 + wm * 16;
#pragma unroll
    for (int mi = 0; mi < 4; ++mi) {
        const int d = dbase + mi * 4 + hi;
        if (d >= DF) continue;
        const float4 b4 = *(const float4*)&bp4[4 * d];
#pragma unroll
        for (int ni = 0; ni < 2; ++ni) {
            const int n = n0 + wn * 32 + ni * 16 + lo;
            if (n >= N_NODES) continue;
            float sr  = acc[mi][ni][0] + b4.x;
            float sz  = acc[mi][ni][1] + b4.y;
            float gin = acc[mi][ni][2] + b4.z;
            float ghn = acc[mi][ni][3] + b4.w;
            float mem = (float)xb[(size_t)n * KA + MSGD + d];  // L2-hot bf16
            float rg  = sigmoidf_(sr);
            float zg  = sigmoidf_(sz);
            float nt  = tanhf(fmaf(rg, ghn, gin));
            mem_upd[(size_t)n * DF + d] = (__bf16)fmaf(zg, mem - nt, nt);
        }
    }
}

// ============================================================
// Kernel 2a: kin build — gather + convert + time-encode, bf16 rows.
// ============================================================
__global__ __launch_bounds__(256) void kin_build_kernel(
    const __bf16* __restrict__ mem_upd, const float* __restrict__ edge_features,
    const float* __restrict__ edge_times, const float* __restrict__ neighbor_times,
    const float* __restrict__ time_w, const float* __restrict__ time_b,
    const int* __restrict__ neighbors, const int* __restrict__ nbr_eidx,
    __bf16* __restrict__ kin)
{
    const long total = (long)NKV_ROWS * 136;
    for (long idx = (long)blockIdx.x * 256 + threadIdx.x; idx < total;
         idx += (long)gridDim.x * 256) {
        const int r  = (int)(idx / 136);
        const int c  = (int)(idx - (long)r * 136) * 4;
        const int rc = min(r, NKV - 1);
        bf16x4 o;
        if (c < DF) {
            const int nbr = neighbors[rc];
            o = *(const bf16x4*)(mem_upd + (size_t)nbr * DF + c);
        } else if (c < 2 * DF) {
            const int eidx = nbr_eidx[rc];
            const float4 v = *(const float4*)(edge_features + (size_t)eidx * DF + (c - DF));
            o[0] = (__bf16)v.x; o[1] = (__bf16)v.y;
            o[2] = (__bf16)v.z; o[3] = (__bf16)v.w;
        } else if (c < KIN_D) {
            const float dt = edge_times[(rc / KNBR) % BATCH] - neighbor_times[rc];
            const float4 tw = *(const float4*)(time_w + (c - 2 * DF));
            const float4 tb = *(const float4*)(time_b + (c - 2 * DF));
            o[0] = (__bf16)cosf(fmaf(dt, tw.x, tb.x));
            o[1] = (__bf16)cosf(fmaf(dt, tw.y, tb.y));
            o[2] = (__bf16)cosf(fmaf(dt, tw.z, tb.z));
            o[3] = (__bf16)cosf(fmaf(dt, tw.w, tb.w));
        } else {
            o[0] = o[1] = o[2] = o[3] = (__bf16)0.f;
        }
        *(bf16x4*)(kin + (size_t)r * KP_KV + c) = o;
    }
}

// ============================================================
// Kernel 2b: KV GEMM v4 (R11-proven) — pure GEMM, 512 thr, 3-buf gl16
// ============================================================
__global__ __launch_bounds__(512) void kv_gemm4_kernel(
    const __bf16* __restrict__ kin, const __bf16* __restrict__ wkvb,
    __bf16* __restrict__ kv)
{
    __shared__ __align__(16) __bf16 Ws[3][128 * 32];
    __shared__ __align__(16) __bf16 Xs[3][128 * 32];

    const int t    = threadIdx.x;
    const int w    = t >> 6, lane = t & 63;
    const int lo   = lane & 15, hi = lane >> 4;
    const int wm   = w & 1;
    const int wn   = w >> 1;

    const int orig = blockIdx.x;
    const int q = NWG_KV >> 3, rr = NWG_KV & 7;
    const int xcd = orig & 7, oidx = orig >> 3;
    const int wgid = (xcd < rr ? xcd * (q + 1) : rr * (q + 1) + (xcd - rr) * q) + oidx;
    const int m_tile = wgid % 3;
    const int n_tile = wgid / 3;
    const int n0 = n_tile * 128;
    const int j0 = m_tile * 128;

    const int srow  = lane >> 2;
    const int sslot = ((lane & 3) ^ ((srow >> 1) & 3)) * 8;

    f32x4 acc[4][2];
#pragma unroll
    for (int mi = 0; mi < 4; ++mi)
#pragma unroll
        for (int ni = 0; ni < 2; ++ni)
            acc[mi][ni] = (f32x4){0.f, 0.f, 0.f, 0.f};

    const __bf16* wbase = wkvb + (size_t)j0 * KP_KV;
    const __bf16* xbase = kin + (size_t)n0 * KP_KV;

#define STAGE(buf, k0)                                                           \
    {                                                                            \
        const int lr = w * 16 + srow;                                            \
        gl16(wbase + (size_t)lr * KP_KV + (k0) + sslot, &Ws[buf][(w * 16) * 32]);\
        gl16(xbase + (size_t)lr * KP_KV + (k0) + sslot, &Xs[buf][(w * 16) * 32]);\
    }

    STAGE(0, 0);
    STAGE(1, 32);

    const int fsa = (hi ^ ((lo >> 1) & 3)) * 8;
    for (int ks = 0; ks < KSTEPS_KV; ++ks) {
        if (ks < KSTEPS_KV - 1) {
            asm volatile("s_waitcnt vmcnt(2)" ::: "memory");
        } else {
            asm volatile("s_waitcnt vmcnt(0)" ::: "memory");
        }
        __builtin_amdgcn_s_barrier();
        if (ks + 2 < KSTEPS_KV) STAGE((ks + 2) % 3, (ks + 2) * 32);

        const int bi = ks % 3;
        bf16x8 af[4], bx_[2];
#pragma unroll
        for (int i = 0; i < 4; ++i)
            af[i]  = *(const bf16x8*)&Ws[bi][(wm * 64 + i * 16 + lo) * 32 + fsa];
#pragma unroll
        for (int i = 0; i < 2; ++i)
            bx_[i] = *(const bf16x8*)&Xs[bi][(wn * 32 + i * 16 + lo) * 32 + fsa];
#pragma unroll
        for (int mi = 0; mi < 4; ++mi)
#pragma unroll
            for (int ni = 0; ni < 2; ++ni)
                acc[mi][ni] = __builtin_amdgcn_mfma_f32_16x16x32_bf16(
                    af[mi], bx_[ni], acc[mi][ni], 0, 0, 0);
    }
#undef STAGE

#pragma unroll
    for (int mi = 0; mi < 4; ++mi) {
        const int jb = j0 + wm * 64 + mi * 16 + hi * 4;
        int off;
        if (jb + 3 < DF)                 off = jb;
        else if (jb >= 192 && jb < 361)  off = jb - 16;
        else continue;
#pragma unroll
        for (int ni = 0; ni < 2; ++ni) {
            const int n = n0 + wn * 32 + ni * 16 + lo;
            if (n >= NKV) continue;
            bf16x4 o;
            o[0] = (__bf16)acc[mi][ni][0];
            o[1] = (__bf16)acc[mi][ni][1];
            o[2] = (__bf16)acc[mi][ni][2];
            o[3] = (__bf16)acc[mi][ni][3];
            *(bf16x4*)(kv + (size_t)n * KVS + off) = o;
        }
    }
}

// ============================================================
// Kernel 3: q projection GEMM v2 — single 192-j tile, 47 blocks.
// ============================================================
__global__ __launch_bounds__(256) void q_gemm_kernel(
    const __bf16* __restrict__ wqb, const __bf16* __restrict__ mem_upd,
    const float* __restrict__ time_b, const int* __restrict__ nodes_cat,
    __bf16* __restrict__ qbuf)
{
    __shared__ __align__(16) __bf16 Ws[192 * 32];
    __shared__ __align__(16) __bf16 Xs[128][32];

    const int t    = threadIdx.x;
    const int w    = t >> 6, lane = t & 63;
    const int lo   = lane & 15, hi = lane >> 4;
    const int wm   = w >> 1, wn = w & 1;
    const int n0   = blockIdx.x * 128;

    const int xrow  = t >> 1, xhalf = t & 1;
    const int nr    = min(n0 + xrow, M3 - 1);
    const __bf16* mrow = mem_upd + (size_t)nodes_cat[nr] * DF;

    const int srow  = lane >> 2;
    const int sslot = ((lane & 3) ^ ((srow >> 1) & 3)) * 8;
    const int fsa   = (hi ^ ((lo >> 1) & 3)) * 8;

    f32x4 acc[6][4];
#pragma unroll
    for (int mi = 0; mi < 6; ++mi)
#pragma unroll
        for (int ni = 0; ni < 4; ++ni)
            acc[mi][ni] = (f32x4){0.f, 0.f, 0.f, 0.f};

    for (int k0 = 0; k0 < 352; k0 += 32) {
#pragma unroll
        for (int qq = 0; qq < 3; ++qq) {
            const int jr = w * 48 + qq * 16 + srow;
            gl16(wqb + (size_t)jr * 352 + k0 + sslot, &Ws[(w * 48 + qq * 16) * 32]);
        }
        bf16x8 x0, x1;
#pragma unroll
        for (int c = 0; c < 4; ++c) {
            const int b = k0 + xhalf * 16 + c * 4;
            __bf16 e0, e1, e2, e3;
            if (b + 3 < DF) {
                bf16x4 h = *(const bf16x4*)(mrow + b);
                e0 = h[0]; e1 = h[1]; e2 = h[2]; e3 = h[3];
            } else if (b >= 176 && b < 348) {
                const float4 tb = *(const float4*)(time_b + (b - 176));
                e0 = (__bf16)cosf(tb.x); e1 = (__bf16)cosf(tb.y);
                e2 = (__bf16)cosf(tb.z); e3 = (__bf16)cosf(tb.w);
            } else {
                e0 = e1 = e2 = e3 = (__bf16)0.f;
            }
            if (c < 2) { x0[c*4]=e0; x0[c*4+1]=e1; x0[c*4+2]=e2; x0[c*4+3]=e3; }
            else { x1[(c-2)*4]=e0; x1[(c-2)*4+1]=e1; x1[(c-2)*4+2]=e2; x1[(c-2)*4+3]=e3; }
        }
        *(bf16x8*)&Xs[xrow][xhalf * 16]     = x0;
        *(bf16x8*)&Xs[xrow][xhalf * 16 + 8] = x1;
        __syncthreads();

        bf16x8 af[6], bx_[4];
#pragma unroll
        for (int i = 0; i < 6; ++i)
            af[i] = *(const bf16x8*)&Ws[(wm * 96 + i * 16 + lo) * 32 + fsa];
#pragma unroll
        for (int i = 0; i < 4; ++i)
            bx_[i] = *(const bf16x8*)&Xs[wn * 64 + i * 16 + lo][hi * 8];
#pragma unroll
        for (int mi = 0; mi < 6; ++mi)
#pragma unroll
            for (int ni = 0; ni < 4; ++ni)
                acc[mi][ni] = __builtin_amdgcn_mfma_f32_16x16x32_bf16(
                    af[mi], bx_[ni], acc[mi][ni], 0, 0, 0);
        __syncthreads();
    }

#pragma unroll
    for (int mi = 0; mi < 6; ++mi) {
        const int jb = wm * 96 + mi * 16 + hi * 4;
        if (jb + 3 >= 176) continue;
#pragma unroll
        for (int ni = 0; ni < 4; ++ni) {
            const int n = n0 + wn * 64 + ni * 16 + lo;
            if (n >= M3) continue;
            bf16x4 o;
            o[0]=(__bf16)acc[mi][ni][0]; o[1]=(__bf16)acc[mi][ni][1];
            o[2]=(__bf16)acc[mi][ni][2]; o[3]=(__bf16)acc[mi][ni][3];
            *(bf16x4*)(qbuf + (size_t)n * 176 + jb) = o;
        }
    }
}

// ============================================================
// Kernel 4: attn_mid v2 — 2 queries per block (3000 blocks)
// ============================================================
__global__ __launch_bounds__(256) void attn_mid_kernel(
    const __bf16* __restrict__ mem_upd, const __bf16* __restrict__ kv,
    const __bf16* __restrict__ qb, const int* __restrict__ neighbors,
    const int* __restrict__ nodes_cat, __bf16* __restrict__ cat)
{
    __shared__ __align__(16) __bf16 kvs[2][KNBR][KVS];
    __shared__ float qs[2][176];
    __shared__ float scl[2][2][KNBR];
    __shared__ float attnl[2][2][KNBR];
    __shared__ int   nbrs[2][KNBR];

    const int i0 = blockIdx.x * 2;
    const int t = threadIdx.x;

    if (t < 2 * KNBR) {
        int q = t / KNBR, kn = t - q * KNBR;
        nbrs[q][kn] = neighbors[(i0 + q) * KNBR + kn];
    }
    for (int idx = t; idx < 352; idx += 256) {
        int q = idx / 176, c = idx - q * 176;
        qs[q][c] = (float)qb[(size_t)(i0 + q) * 176 + c];
    }
    {
        const uint4* src = (const uint4*)(kv + (size_t)i0 * KNBR * KVS);
        uint4* dst = (uint4*)&kvs[0][0][0];
        for (int idx = t; idx < 2 * KNBR * KVS / 8; idx += 256) dst[idx] = src[idx];
    }
    __syncthreads();

    if (t < 4 * KNBR) {
        int q = t / (2 * KNBR);
        int r = t - q * 2 * KNBR;
        int h = r / KNBR, kn = r - h * KNBR;
        float s = 0.f;
#pragma unroll 2
        for (int j = 0; j < DH; ++j)
            s = fmaf(qs[q][h * DH + j], (float)kvs[q][kn][h * DH + j], s);
        s /= sqrtf((float)DH);
        scl[q][h][kn] = (nbrs[q][kn] > 0) ? s : -1e9f;
    }
    __syncthreads();
    if (t < 4) {
        int q = t >> 1, h = t & 1;
        float m = -INFINITY;
        for (int kn = 0; kn < KNBR; ++kn) m = fmaxf(m, scl[q][h][kn]);
        float se = 0.f;
        for (int kn = 0; kn < KNBR; ++kn) se += expf(scl[q][h][kn] - m);
        float inv = 1.f / se;
        for (int kn = 0; kn < KNBR; ++kn)
            attnl[q][h][kn] = expf(scl[q][h][kn] - m) * inv;
    }
    __syncthreads();
    for (int idx = t; idx < 2 * DF; idx += 256) {
        int q = idx / DF, d = idx - q * DF;
        int h = d / DH;
        float cx = 0.f;
#pragma unroll
        for (int kn = 0; kn < KNBR; ++kn)
            cx = fmaf(attnl[q][h][kn], (float)kvs[q][kn][176 + d], cx);
        cat[(size_t)(i0 + q) * 352 + d] = (__bf16)cx;
        cat[(size_t)(i0 + q) * 352 + 176 + d] =
            mem_upd[(size_t)nodes_cat[i0 + q] * DF + d];
    }
    if (t < 8) {
        int q = t >> 2, r = t & 3;
        cat[(size_t)(i0 + q) * 352 + 172 + r] = (__bf16)0.f;
        cat[(size_t)(i0 + q) * 352 + 348 + r] = (__bf16)0.f;
    }
}

// ============================================================
// Kernel 5: fused merge+emb — 64-row n-tiles (94 blocks)
// ============================================================
__global__ __launch_bounds__(256) void merge_emb_kernel(
    const __bf16* __restrict__ cat, const __bf16* __restrict__ wm1b,
    const __bf16* __restrict__ wm2b, const float* __restrict__ bm1p,
    const float* __restrict__ bm2p, __bf16* __restrict__ embb)
{
    __shared__ __align__(16) __bf16 Ws[192 * 32];
    __shared__ __align__(16) __bf16 Xs[64 * 32];
    __shared__ __align__(16) __bf16 h1[64 * 200];

    const int t    = threadIdx.x;
    const int w    = t >> 6, lane = t & 63;
    const int lo   = lane & 15, hi = lane >> 4;
    const int wm   = w >> 1, wn = w & 1;
    const int n0   = blockIdx.x * 64;

    const int srow  = lane >> 2;
    const int sslot = ((lane & 3) ^ ((srow >> 1) & 3)) * 8;
    const int fsa   = (hi ^ ((lo >> 1) & 3)) * 8;

    f32x4 acc[6][2];
#pragma unroll
    for (int mi = 0; mi < 6; ++mi)
#pragma unroll
        for (int ni = 0; ni < 2; ++ni)
            acc[mi][ni] = (f32x4){0.f, 0.f, 0.f, 0.f};

    for (int k0 = 0; k0 < 352; k0 += 32) {
#pragma unroll
        for (int qq = 0; qq < 3; ++qq) {
            const int jr = w * 48 + qq * 16 + srow;
            gl16(wm1b + (size_t)jr * 352 + k0 + sslot, &Ws[(w * 48 + qq * 16) * 32]);
        }
        {
            const int r = w * 16 + srow;
            const int nr = min(n0 + r, M3 - 1);
            gl16(cat + (size_t)nr * 352 + k0 + sslot, &Xs[(w * 16) * 32]);
        }
        asm volatile("s_waitcnt vmcnt(0)" ::: "memory");
        __syncthreads();

        bf16x8 af[6], bx_[2];
#pragma unroll
        for (int i = 0; i < 6; ++i)
            af[i] = *(const bf16x8*)&Ws[(wm * 96 + i * 16 + lo) * 32 + fsa];
#pragma unroll
        for (int i = 0; i < 2; ++i)
            bx_[i] = *(const bf16x8*)&Xs[(wn * 32 + i * 16 + lo) * 32 + fsa];
#pragma unroll
        for (int mi = 0; mi < 6; ++mi)
#pragma unroll
            for (int ni = 0; ni < 2; ++ni)
                acc[mi][ni] = __builtin_amdgcn_mfma_f32_16x16x32_bf16(
                    af[mi], bx_[ni], acc[mi][ni], 0, 0, 0);
        __syncthreads();
    }

#pragma unroll
    for (int mi = 0; mi < 6; ++mi) {
        const int jb = wm * 96 + mi * 16 + hi * 4;
        const float4 b4 = *(const float4*)(bm1p + jb);
#pragma unroll
        for (int ni = 0; ni < 2; ++ni) {
            const int nl = wn * 32 + ni * 16 + lo;
            bf16x4 o;
            o[0] = (__bf16)fmaxf(acc[mi][ni][0] + b4.x, 0.f);
            o[1] = (__bf16)fmaxf(acc[mi][ni][1] + b4.y, 0.f);
            o[2] = (__bf16)fmaxf(acc[mi][ni][2] + b4.z, 0.f);
            o[3] = (__bf16)fmaxf(acc[mi][ni][3] + b4.w, 0.f);
            *(bf16x4*)&h1[nl * 200 + jb] = o;
        }
    }
    __syncthreads();

    f32x4 acc2[6][2];
#pragma unroll
    for (int mi = 0; mi < 6; ++mi)
#pragma unroll
        for (int ni = 0; ni < 2; ++ni)
            acc2[mi][ni] = (f32x4){0.f, 0.f, 0.f, 0.f};

    for (int k0 = 0; k0 < 192; k0 += 32) {
#pragma unroll
        for (int qq = 0; qq < 3; ++qq) {
            const int jr = w * 48 + qq * 16 + srow;
            gl16(wm2b + (size_t)jr * 192 + k0 + sslot, &Ws[(w * 48 + qq * 16) * 32]);
        }
        asm volatile("s_waitcnt vmcnt(0)" ::: "memory");
        __syncthreads();

        bf16x8 af[6], bx_[2];
#pragma unroll
        for (int i = 0; i < 6; ++i)
            af[i] = *(const bf16x8*)&Ws[(wm * 96 + i * 16 + lo) * 32 + fsa];
#pragma unroll
        for (int i = 0; i < 2; ++i)
            bx_[i] = *(const bf16x8*)&h1[(wn * 32 + i * 16 + lo) * 200 + k0 + hi * 8];
#pragma unroll
        for (int mi = 0; mi < 6; ++mi)
#pragma unroll
            for (int ni = 0; ni < 2; ++ni)
                acc2[mi][ni] = __builtin_amdgcn_mfma_f32_16x16x32_bf16(
                    af[mi], bx_[ni], acc2[mi][ni], 0, 0, 0);
        __syncthreads();
    }

#pragma unroll
    for (int mi = 0; mi < 6; ++mi) {
        const int jb = wm * 96 + mi * 16 + hi * 4;
        if (jb + 3 >= 176) continue;
        const float4 b4 = *(const float4*)(bm2p + jb);
#pragma unroll
        for (int ni = 0; ni < 2; ++ni) {
            const int n = n0 + wn * 32 + ni * 16 + lo;
            if (n >= M3) continue;
            bf16x4 o;
            o[0] = (__bf16)(acc2[mi][ni][0] + b4.x);
            o[1] = (__bf16)(acc2[mi][ni][1] + b4.y);
            o[2] = (__bf16)(acc2[mi][ni][2] + b4.z);
            o[3] = (__bf16)(acc2[mi][ni][3] + b4.w);
            *(bf16x4*)(embb + (size_t)n * 176 + jb) = o;
        }
    }
}

// ============================================================
// Kernel 6: fused affinity GEMM + dot + sigmoid (32 blocks)
// ============================================================
__global__ __launch_bounds__(256) void aff_fused_kernel(
    const __bf16* __restrict__ embb, const __bf16* __restrict__ waffb,
    const float* __restrict__ baffp, const float* __restrict__ aff_w2,
    const float* __restrict__ aff_b2, float* __restrict__ out)
{
    __shared__ __align__(16) __bf16 Ws[192 * 32];
    __shared__ __align__(16) __bf16 Xs[128 * 32];
    __shared__ float sred[2][2][4][16];

    const int t    = threadIdx.x;
    const int w    = t >> 6, lane = t & 63;
    const int lo   = lane & 15, hi = lane >> 4;
    const int wm   = w >> 1, wn = w & 1;
    const int n0   = blockIdx.x * 128;

    const int srow  = lane >> 2;
    const int sslot = ((lane & 3) ^ ((srow >> 1) & 3)) * 8;
    const int fsa   = (hi ^ ((lo >> 1) & 3)) * 8;

    f32x4 acc[6][4];
#pragma unroll
    for (int mi = 0; mi < 6; ++mi)
#pragma unroll
        for (int ni = 0; ni < 4; ++ni)
            acc[mi][ni] = (f32x4){0.f, 0.f, 0.f, 0.f};

    for (int k0 = 0; k0 < 352; k0 += 32) {
#pragma unroll
        for (int qq = 0; qq < 3; ++qq) {
            const int jr = w * 48 + qq * 16 + srow;
            gl16(waffb + (size_t)jr * 352 + k0 + sslot, &Ws[(w * 48 + qq * 16) * 32]);
        }
#pragma unroll
        for (int qq = 0; qq < 2; ++qq) {
            const int r = w * 32 + qq * 16 + srow;
            const int nr = min(n0 + r, 2 * BATCH - 1);
            const int s  = (nr < BATCH) ? nr : nr - BATCH;
            const int col = k0 + sslot;
            const __bf16* src = (col < 176)
                ? embb + (size_t)s * 176 + col
                : embb + (size_t)(nr + BATCH) * 176 + (col - 176);
            gl16(src, &Xs[(w * 32 + qq * 16) * 32]);
        }
        asm volatile("s_waitcnt vmcnt(0)" ::: "memory");
        __syncthreads();

        bf16x8 af[6], bx_[4];
#pragma unroll
        for (int i = 0; i < 6; ++i)
            af[i] = *(const bf16x8*)&Ws[(wm * 96 + i * 16 + lo) * 32 + fsa];
#pragma unroll
        for (int i = 0; i < 4; ++i)
            bx_[i] = *(const bf16x8*)&Xs[(wn * 64 + i * 16 + lo) * 32 + fsa];
#pragma unroll
        for (int mi = 0; mi < 6; ++mi)
#pragma unroll
            for (int ni = 0; ni < 4; ++ni)
                acc[mi][ni] = __builtin_amdgcn_mfma_f32_16x16x32_bf16(
                    af[mi], bx_[ni], acc[mi][ni], 0, 0, 0);
        __syncthreads();
    }

    float ps[4] = {0.f, 0.f, 0.f, 0.f};
#pragma unroll
    for (int mi = 0; mi < 6; ++mi) {
        const int jb = wm * 96 + mi * 16 + hi * 4;
#pragma unroll
        for (int r = 0; r < 4; ++r) {
            const int j = jb + r;
            const float w2v = (j < DF) ? aff_w2[j] : 0.f;
            const float bb  = baffp[j];
#pragma unroll
            for (int ni = 0; ni < 4; ++ni)
                ps[ni] += fmaxf(acc[mi][ni][r] + bb, 0.f) * w2v;
        }
    }
#pragma unroll
    for (int ni = 0; ni < 4; ++ni) {
        ps[ni] += __shfl_xor(ps[ni], 16, 64);
        ps[ni] += __shfl_xor(ps[ni], 32, 64);
    }
    if (hi == 0) {
#pragma unroll
        for (int ni = 0; ni < 4; ++ni) sred[wm][wn][ni][lo] = ps[ni];
    }
    __syncthreads();
    if (t < 128) {
        const int n = n0 + t;
        if (n < 2 * BATCH) {
            const int wn2 = t >> 6, ni = (t >> 4) & 3, lo2 = t & 15;
            float s = sred[0][wn2][ni][lo2] + sred[1][wn2][ni][lo2] + aff_b2[0];
            out[n] = 1.f / (1.f + expf(-s));
        }
    }
}

// ============================================================
extern "C" void kernel_launch(void* const* d_in, const int* in_sizes, int n_in,
                              void* d_out, int out_size, void* d_ws, size_t ws_size,
                              hipStream_t stream)
{
    (void)in_sizes; (void)n_in; (void)out_size; (void)ws_size;
    const float* memory         = (const float*)d_in[0];
    const float* messages       = (const float*)d_in[1];
    const float* edge_features  = (const float*)d_in[2];
    const float* edge_times     = (const float*)d_in[3];
    const float* neighbor_times = (const float*)d_in[4];
    const float* time_w         = (const float*)d_in[5];
    const float* time_b         = (const float*)d_in[6];
    const float* gru_w_ih       = (const float*)d_in[7];
    const float* gru_w_hh       = (const float*)d_in[8];
    const float* gru_b_ih       = (const float*)d_in[9];
    const float* gru_b_hh       = (const float*)d_in[10];
    const float* w_q            = (const float*)d_in[11];
    const float* w_k            = (const float*)d_in[12];
    const float* w_v            = (const float*)d_in[13];
    const float* w_o            = (const float*)d_in[14];
    const float* merge_w1       = (const float*)d_in[15];
    const float* merge_b1       = (const float*)d_in[16];
    const float* merge_w2       = (const float*)d_in[17];
    const float* merge_b2       = (const float*)d_in[18];
    const float* aff_w1         = (const float*)d_in[19];
    const float* aff_b1         = (const float*)d_in[20];
    const float* aff_w2         = (const float*)d_in[21];
    const float* aff_b2         = (const float*)d_in[22];
    const int* src_nodes        = (const int*)d_in[23];
    const int* dst_nodes        = (const int*)d_in[24];
    const int* neg_nodes        = (const int*)d_in[25];
    const int* neighbors        = (const int*)d_in[26];
    const int* nbr_eidx         = (const int*)d_in[27];

    float* ws       = (float*)d_ws;
    __bf16* wpb     = (__bf16*)(ws + WPB_OFF);
    float* bp4      = ws + BP4_OFF;
    __bf16* wkvb    = (__bf16*)(ws + WKV_OFF);
    __bf16* mem_upd = (__bf16*)(ws + MU_OFF);
    __bf16* xbuf    = (__bf16*)(ws + UNI_OFF);
    __bf16* kv      = (__bf16*)(ws + KV_OFF);
    __bf16* qbuf    = (__bf16*)(ws + QB_OFF);
    __bf16* cat     = (__bf16*)(ws + CAT_OFF);
    __bf16* embb    = (__bf16*)(ws + EMBB_OFF);
    __bf16* wqb     = (__bf16*)(ws + WQB_OFF);
    __bf16* wm1b    = (__bf16*)(ws + WM1B_OFF);
    __bf16* wm2b    = (__bf16*)(ws + WM2B_OFF);
    __bf16* waffb   = (__bf16*)(ws + WAFFB_OFF);
    float* bm1p     = ws + BM1P_OFF;
    float* bm2p     = ws + BM2P_OFF;
    float* baffp    = ws + BAFFP_OFF;
    int*   nodes_cat= (int*)(ws + NODES_OFF);
    __bf16* kin     = (__bf16*)(ws + KIN_OFF);
    float* out      = (float*)d_out;

    prep_all_kernel<<<(JP * KA + 255) / 256, 256, 0, stream>>>(
        gru_w_ih, gru_w_hh, gru_b_ih, gru_b_hh, w_k, w_v, wpb, bp4, wkvb);
    conv_kernel<<<2048, 256, 0, stream>>>(messages, memory, xbuf);
    gru_mfma5_kernel<<<NWG_GRU, 512, 0, stream>>>(xbuf, wpb, bp4, mem_upd);
    prep_tail_kernel<<<(192 * 352 + 255) / 256, 256, 0, stream>>>(
        w_q, w_o, merge_w1, merge_w2, aff_w1, merge_b1, merge_b2, aff_b1,
        src_nodes, dst_nodes, neg_nodes,
        wqb, wm1b, wm2b, waffb, bm1p, bm2p, baffp, nodes_cat);
    kin_build_kernel<<<2048, 256, 0, stream>>>(
        mem_upd, edge_features, edge_times, neighbor_times, time_w, time_b,
        neighbors, nbr_eidx, kin);
    kv_gemm4_kernel<<<NWG_KV, 512, 0, stream>>>(kin, wkvb, kv);
    q_gemm_kernel<<<47, 256, 0, stream>>>(wqb, mem_upd, time_b, nodes_cat, qbuf);
    attn_mid_kernel<<<M3 / 2, 256, 0, stream>>>(
        mem_upd, kv, qbuf, neighbors, nodes_cat, cat);
    merge_emb_kernel<<<94, 256, 0, stream>>>(cat, wm1b, wm2b, bm1p, bm2p, embb);
    aff_fused_kernel<<<32, 256, 0, stream>>>(embb, waffb, baffp, aff_w2, aff_b2, out);
}